// Round 9
// baseline (229.378 us; speedup 1.0000x reference)
//
#include <hip/hip_runtime.h>
#include <hip/hip_bf16.h>

// RoPEAttention B=2 S=2048 D=1024 H=16 HD=64, fp32 in/out.
// R9: flash 128-key tiles (half the barriers, 2x chains per barrier);
//     gemm_out po register-prefetch; XCD swizzle on both GEMMs.
// ws (shorts): qbh[0,4M) kbh[4M,8M) vt[8M,12M) xb[16M,20M)
//              wqkvb[20M,23M) wob[23M,24M) po[24M,32M) pl(fp32) after.

#define B_ 2
#define S_ 2048
#define D_ 1024
#define H_ 16
#define HD_ 64
#define M_ (B_*S_)
#define SPLIT_ 2
#define KSPAN_ (S_/SPLIT_)    // 1024 keys per split
#define KTILE_ 128

typedef __attribute__((ext_vector_type(8))) short short8;
typedef __attribute__((ext_vector_type(4))) short short4v;
typedef __attribute__((ext_vector_type(4))) float f32x4;
typedef __attribute__((ext_vector_type(4))) _Float16 half4;
typedef __attribute__((ext_vector_type(8))) _Float16 half8;

static __device__ __forceinline__ short f2bf(float f) {
    __hip_bfloat16 h = __float2bfloat16(f);
    return *reinterpret_cast<short*>(&h);
}
static __device__ __forceinline__ short f2h(float f) {
    _Float16 h = (_Float16)f;
    return *reinterpret_cast<short*>(&h);
}

typedef __attribute__((address_space(1))) const unsigned int gu32_t;
typedef __attribute__((address_space(3))) unsigned int lu32_t;
static __device__ __forceinline__ void gld16(const short* g, short* l) {
    __builtin_amdgcn_global_load_lds((gu32_t*)g, (lu32_t*)l, 16, 0, 0);
}

// ---------------- fp32 -> bf16 convert: x, wq|wk|wv (concat), wo ----------------
__global__ __launch_bounds__(256)
void convert_bf16(const float* __restrict__ x,
                  const float* __restrict__ wq, const float* __restrict__ wk,
                  const float* __restrict__ wv, const float* __restrict__ wo,
                  short* __restrict__ xb, short* __restrict__ wqkvb, short* __restrict__ wob)
{
    const size_t t4 = ((size_t)blockIdx.x * 256 + threadIdx.x) * 4;
    const float* src; short* dst; size_t off, doff;
    if (t4 < 4194304)      { src = x;  dst = xb;    off = t4;           doff = t4; }
    else if (t4 < 5242880) { src = wq; dst = wqkvb; off = t4 - 4194304; doff = t4 - 4194304; }
    else if (t4 < 6291456) { src = wk; dst = wqkvb; off = t4 - 5242880; doff = t4 - 4194304; }
    else if (t4 < 7340032) { src = wv; dst = wqkvb; off = t4 - 6291456; doff = t4 - 4194304; }
    else                   { src = wo; dst = wob;   off = t4 - 7340032; doff = t4 - 7340032; }
    float4 v = *(const float4*)(src + off);
    short4v s = { f2bf(v.x), f2bf(v.y), f2bf(v.z), f2bf(v.w) };
    *(short4v*)(dst + doff) = s;
}

// ---------------- bf16 MFMA GEMM NT 128x128 (qkv fused, N=3072), XCD-swizzled ----------------
// Epilogue: which==0/1 -> fused RMSNorm+RoPE -> Qb/Kb bf16 [B,H,S,HD]
//           which==2   -> Vt f16 [B,H,HD,S]
__global__ __launch_bounds__(256)
void gemm_qkv(const short* __restrict__ A, const short* __restrict__ Bw,
              short* __restrict__ Qb, short* __restrict__ Kb, short* __restrict__ Vt,
              const float* __restrict__ q_scale, const float* __restrict__ k_scale,
              const float* __restrict__ rope_cos, const float* __restrict__ rope_sin)
{
    __shared__ __align__(16) short As[128*32];
    __shared__ __align__(16) short Bs[128*32];
    const int tid = threadIdx.x;
    const int w = tid >> 6, lane = tid & 63, quad = lane >> 4, l16 = lane & 15;
    const int wr = w >> 1, wc = w & 1;
    // XCD swizzle: 3 weight-column-tiles per XCD -> weight L2 locality
    const int id  = blockIdx.x;
    const int xcd = id & 7, j8 = id >> 3;
    const int by  = xcd*3 + (j8 >> 5);
    const int bx  = j8 & 31;
    const int bm0 = bx * 128, bn0 = by * 128;

    const int srow = tid >> 2;
    const int skch = (tid & 3) * 8;
    const short* gA0 = A  + (size_t)(bm0 + srow) * 1024 + skch;
    const short* gA1 = A  + (size_t)(bm0 + 64 + srow) * 1024 + skch;
    const short* gB0 = Bw + (size_t)(bn0 + srow) * 1024 + skch;
    const short* gB1 = Bw + (size_t)(bn0 + 64 + srow) * 1024 + skch;
    short* lA0 = As + w*512;
    short* lA1 = As + 2048 + w*512;
    short* lB0 = Bs + w*512;
    short* lB1 = Bs + 2048 + w*512;

    f32x4 acc[4][4];
    #pragma unroll
    for (int i = 0; i < 4; ++i)
        #pragma unroll
        for (int j = 0; j < 4; ++j) acc[i][j] = (f32x4){0.f,0.f,0.f,0.f};

    for (int k0 = 0; k0 < 1024; k0 += 32) {
        __syncthreads();
        gld16(gA0 + k0, lA0);
        gld16(gA1 + k0, lA1);
        gld16(gB0 + k0, lB0);
        gld16(gB1 + k0, lB1);
        __syncthreads();
        short8 af[4], bfr[4];
        #pragma unroll
        for (int i = 0; i < 4; ++i)
            af[i] = *(const short8*)(As + (wr*64 + i*16 + l16)*32 + quad*8);
        #pragma unroll
        for (int j = 0; j < 4; ++j)
            bfr[j] = *(const short8*)(Bs + (wc*64 + j*16 + l16)*32 + quad*8);
        #pragma unroll
        for (int i = 0; i < 4; ++i)
            #pragma unroll
            for (int j = 0; j < 4; ++j)
                acc[i][j] = __builtin_amdgcn_mfma_f32_16x16x32_bf16(af[i], bfr[j], acc[i][j], 0, 0, 0);
    }

    const int nbase = bn0 + wc*64;
    const int which = nbase >> 10;
    const int h     = (nbase & 1023) >> 6;

    if (which < 2) {
        const float* sc = which ? k_scale : q_scale;
        short* dst      = which ? Kb : Qb;
        const float fold = which ? 1.0f : 0.18033688011112042f;  // q: (1/8)*log2(e)
        float scv[4];
        #pragma unroll
        for (int j = 0; j < 4; ++j) scv[j] = sc[j*16 + l16];
        #pragma unroll
        for (int i = 0; i < 4; ++i) {
            #pragma unroll
            for (int r = 0; r < 4; ++r) {
                const int m = bm0 + wr*64 + i*16 + quad*4 + r;
                const int b = m >> 11, s = m & (S_-1);
                float ss = 0.f;
                #pragma unroll
                for (int j = 0; j < 4; ++j) ss += acc[i][j][r] * acc[i][j][r];
                #pragma unroll
                for (int msk = 1; msk <= 8; msk <<= 1) ss += __shfl_xor(ss, msk, 64);
                const float rn = rsqrtf(ss * (1.0f/64.0f) + 1e-6f);
                #pragma unroll
                for (int j = 0; j < 4; ++j) {
                    const int hd = j*16 + l16;
                    const float nv = acc[i][j][r] * rn * scv[j];
                    const float c  = rope_cos[s*32 + (hd >> 1)];
                    const float sn = rope_sin[s*32 + (hd >> 1)];
                    const float partner = __shfl_xor(nv, 1, 64);
                    const float o = (hd & 1) ? (partner * sn + nv * c) : (nv * c - partner * sn);
                    dst[(((size_t)b*H_ + h)*S_ + s)*HD_ + hd] = f2bf(o * fold);
                }
            }
        }
    } else {
        #pragma unroll
        for (int i = 0; i < 4; ++i)
            #pragma unroll
            for (int r = 0; r < 4; ++r) {
                const int m = bm0 + wr*64 + i*16 + quad*4 + r;
                const int b = m >> 11, s = m & (S_-1);
                #pragma unroll
                for (int j = 0; j < 4; ++j) {
                    const int hd = j*16 + l16;
                    Vt[(((size_t)b*H_ + h)*HD_ + hd)*S_ + s] = f2h(acc[i][j][r]);
                }
            }
    }
}

// ---------------- out-proj GEMM 64x128, combine fused, po prefetched, XCD-swizzled ----------------
__global__ __launch_bounds__(256)
void gemm_out(const short* __restrict__ po, const float* __restrict__ pl,
              const short* __restrict__ Bw, float* __restrict__ C)
{
    __shared__ __align__(16) short As[64*32];
    __shared__ __align__(16) short Bs[128*32];
    const int tid = threadIdx.x;
    const int w = tid >> 6, lane = tid & 63, quad = lane >> 4, l16 = lane & 15;
    // XCD swizzle: weight-column-tile == XCD (N/128 == 8 tiles)
    const int id  = blockIdx.x;
    const int bn0 = (id & 7) * 128;
    const int bm0 = (id >> 3) * 64;

    const int srow = tid >> 2;
    const int skch = (tid & 3) * 8;
    const int m = bm0 + srow;
    const int b = m >> 11, s = m & (S_-1);
    const short* gB0 = Bw + (size_t)(bn0 + srow) * 1024 + skch;
    const short* gB1 = Bw + (size_t)(bn0 + 64 + srow) * 1024 + skch;
    short* lB0 = Bs + w*512;
    short* lB1 = Bs + 2048 + w*512;

    float inv[16];
    #pragma unroll
    for (int h = 0; h < 16; ++h)
        inv[h] = 1.0f / (pl[((size_t)(b*16 + h))*S_ + s] + pl[65536 + ((size_t)(b*16 + h))*S_ + s]);

    f32x4 acc[4][2];
    #pragma unroll
    for (int i = 0; i < 4; ++i) {
        acc[i][0] = (f32x4){0.f,0.f,0.f,0.f};
        acc[i][1] = (f32x4){0.f,0.f,0.f,0.f};
    }

    // prefetch k0=0 po chunks
    half8 c0 = *(const half8*)(po +            (size_t)m*1024 + skch);
    half8 c1 = *(const half8*)(po + 4194304 + (size_t)m*1024 + skch);

    for (int k0 = 0; k0 < 1024; k0 += 32) {
        const int h = k0 >> 6;          // head uniform per iter (skch+7 <= 31)
        short8 a;
        #pragma unroll
        for (int j = 0; j < 8; ++j)
            a[j] = f2bf(((float)c0[j] + (float)c1[j]) * inv[h]);
        __syncthreads();
        *(short8*)(As + srow*32 + skch) = a;
        gld16(gB0 + k0, lB0);
        gld16(gB1 + k0, lB1);
        __syncthreads();
        if (k0 < 1024 - 32) {           // issue next po loads before MFMA block
            c0 = *(const half8*)(po +            (size_t)m*1024 + k0 + 32 + skch);
            c1 = *(const half8*)(po + 4194304 + (size_t)m*1024 + k0 + 32 + skch);
        }
        short8 af[4], bfr[2];
        #pragma unroll
        for (int i = 0; i < 4; ++i)
            af[i] = *(const short8*)(As + (i*16 + l16)*32 + quad*8);
        #pragma unroll
        for (int j = 0; j < 2; ++j)
            bfr[j] = *(const short8*)(Bs + (w*32 + j*16 + l16)*32 + quad*8);
        #pragma unroll
        for (int i = 0; i < 4; ++i)
            #pragma unroll
            for (int j = 0; j < 2; ++j)
                acc[i][j] = __builtin_amdgcn_mfma_f32_16x16x32_bf16(af[i], bfr[j], acc[i][j], 0, 0, 0);
    }

    #pragma unroll
    for (int i = 0; i < 4; ++i)
        #pragma unroll
        for (int r = 0; r < 4; ++r) {
            const int mm = bm0 + i*16 + quad*4 + r;
            #pragma unroll
            for (int j = 0; j < 2; ++j) {
                const int n = bn0 + w*32 + j*16 + l16;
                C[(size_t)mm*1024 + n] = acc[i][j][r];
            }
        }
}

// ---------------- MFMA flash attention partial, split-K=2, 128-key tiles, XCD-swizzled ----------------
__global__ __launch_bounds__(256)
void flash_mfma(const short* __restrict__ qb, const short* __restrict__ kb,
                const short* __restrict__ vt, short* __restrict__ po, float* __restrict__ pl)
{
    __shared__ __align__(16) short Ks[128*64];   // [key][d] swizzled (8-chunk, key&7)
    __shared__ __align__(16) short Vs[64*128];   // f16 [d][key] swizzled (8-chunk, d&15)

    const int id   = blockIdx.x;
    const int xcd  = id & 7;
    const int rest = id >> 3;
    const int qblk = rest & 15;               // 16 q-blocks of 128
    const int g    = (rest >> 4) * 8 + xcd;   // (bh,sp) group 0..63
    const int bh   = g >> 1;
    const int sp   = g & 1;

    const int tid  = threadIdx.x;
    const int wv   = tid >> 6;
    const int lane = tid & 63;
    const int quad = lane >> 4;
    const int l16  = lane & 15;
    const int b    = bh >> 4, h = bh & (H_-1);
    const int q0   = qblk * 128 + wv * 32;
    const int kt0  = sp * KSPAN_;
    const size_t hbase = (size_t)bh * S_ * HD_;
    const size_t vbase = (size_t)bh * HD_ * S_;
    short* po_sp = po + (size_t)sp * 4194304;
    float* pl_sp = pl + (size_t)sp * 65536;

    short8 qfrag[2][2];
    #pragma unroll
    for (int qf = 0; qf < 2; ++qf)
        #pragma unroll
        for (int c = 0; c < 2; ++c)
            qfrag[qf][c] = *(const short8*)(qb + hbase + (size_t)(q0 + qf*16 + l16)*HD_ + c*32 + quad*8);

    f32x4 Oacc[2][4];
    #pragma unroll
    for (int qf = 0; qf < 2; ++qf)
        #pragma unroll
        for (int dt = 0; dt < 4; ++dt) Oacc[qf][dt] = (f32x4){0.f,0.f,0.f,0.f};
    float l_lane[2] = {0.f, 0.f};

    // staging decomposition: K chunks c=tid+i*256: key=c>>3, dch=c&7
    //                        V chunks c=tid+i*256: d=c>>4, kch=c&15
    short8 rk[4], rv[4];
    #pragma unroll
    for (int i = 0; i < 4; ++i) {
        const int ck = tid + i*256;
        rk[i] = *(const short8*)(kb + hbase + (size_t)(kt0 + (ck >> 3))*HD_ + (ck & 7)*8);
        rv[i] = *(const short8*)(vt + vbase + (size_t)(ck >> 4)*S_ + kt0 + (ck & 15)*8);
    }

    #pragma unroll 1
    for (int t = 0; t < KSPAN_/KTILE_; ++t) {
        __syncthreads();
        #pragma unroll
        for (int i = 0; i < 4; ++i) {
            const int ck = tid + i*256;
            const int key = ck >> 3, dch = ck & 7;
            *(short8*)(Ks + key*64 + ((dch ^ (key & 7)) << 3)) = rk[i];
            const int d = ck >> 4, kch = ck & 15;
            *(short8*)(Vs + d*128 + ((kch ^ (d & 15)) << 3)) = rv[i];
        }
        __syncthreads();
        if (t < KSPAN_/KTILE_ - 1) {
            const int ktn = kt0 + (t+1)*KTILE_;
            #pragma unroll
            for (int i = 0; i < 4; ++i) {
                const int ck = tid + i*256;
                rk[i] = *(const short8*)(kb + hbase + (size_t)(ktn + (ck >> 3))*HD_ + (ck & 7)*8);
                rv[i] = *(const short8*)(vt + vbase + (size_t)(ck >> 4)*S_ + ktn + (ck & 15)*8);
            }
        }

        #pragma unroll
        for (int st = 0; st < 8; ++st) {
            short8 kf0 = *(const short8*)(Ks + (st*16 + l16)*64 + (((quad    ) ^ (l16 & 7)) << 3));
            short8 kf1 = *(const short8*)(Ks + (st*16 + l16)*64 + (((4 + quad) ^ (l16 & 7)) << 3));
            const int kch = st*2 + (quad >> 1);
            const int sw  = ((kch ^ l16) << 3) + (quad & 1)*4;
            half4 va[4];
            #pragma unroll
            for (int dt = 0; dt < 4; ++dt)
                va[dt] = *(const half4*)(Vs + (dt*16 + l16)*128 + sw);
            #pragma unroll
            for (int qf = 0; qf < 2; ++qf) {
                f32x4 acc = (f32x4){0.f,0.f,0.f,0.f};
                acc = __builtin_amdgcn_mfma_f32_16x16x32_bf16(kf0, qfrag[qf][0], acc, 0, 0, 0);
                acc = __builtin_amdgcn_mfma_f32_16x16x32_bf16(kf1, qfrag[qf][1], acc, 0, 0, 0);
                half4 pb;
                #pragma unroll
                for (int r = 0; r < 4; ++r) {
                    float p = __builtin_amdgcn_exp2f(acc[r] - 12.0f);
                    l_lane[qf] += p;
                    pb[r] = (_Float16)p;
                }
                #pragma unroll
                for (int dt = 0; dt < 4; ++dt)
                    Oacc[qf][dt] = __builtin_amdgcn_mfma_f32_16x16x16f16(va[dt], pb, Oacc[qf][dt], 0, 0, 0);
            }
        }
    }

    #pragma unroll
    for (int qf = 0; qf < 2; ++qf) {
        l_lane[qf] += __shfl_xor(l_lane[qf], 16, 64);
        l_lane[qf] += __shfl_xor(l_lane[qf], 32, 64);
        if (quad == 0) pl_sp[(size_t)bh*S_ + q0 + qf*16 + l16] = l_lane[qf];
    }
    #pragma unroll
    for (int qf = 0; qf < 2; ++qf) {
        const int s = q0 + qf*16 + l16;
        #pragma unroll
        for (int dt = 0; dt < 4; ++dt) {
            short4v o;
            #pragma unroll
            for (int r = 0; r < 4; ++r) o[r] = f2h(Oacc[qf][dt][r]);
            *(short4v*)(po_sp + (((size_t)b*S_ + s)*H_ + h)*HD_ + dt*16 + quad*4) = o;
        }
    }
}

extern "C" void kernel_launch(void* const* d_in, const int* in_sizes, int n_in,
                              void* d_out, int out_size, void* d_ws, size_t ws_size,
                              hipStream_t stream)
{
    (void)in_sizes; (void)n_in; (void)out_size; (void)ws_size;
    const float* x        = (const float*)d_in[0];
    const float* wq       = (const float*)d_in[1];
    const float* wk       = (const float*)d_in[2];
    const float* wv       = (const float*)d_in[3];
    const float* wo       = (const float*)d_in[4];
    const float* q_scale  = (const float*)d_in[5];
    const float* k_scale  = (const float*)d_in[6];
    const float* rope_cos = (const float*)d_in[7];
    const float* rope_sin = (const float*)d_in[8];
    float* out = (float*)d_out;
    short* ws  = (short*)d_ws;

    short* qbh   = ws;                 // 4M shorts
    short* kbh   = ws + 4194304;
    short* vt    = ws + 8388608;
    short* xb    = ws + 16777216;
    short* wqkvb = ws + 20971520;      // 3M shorts
    short* wob   = ws + 24117248;      // 1M shorts
    short* po    = ws + 25165824;      // 2 x 4M shorts (f16)
    float* pl    = (float*)(ws + 33554432);  // 2 x 64K floats

    convert_bf16<<<dim3(8192), 256, 0, stream>>>(x, wq, wk, wv, wo, xb, wqkvb, wob);
    gemm_qkv<<<dim3((M_/128)*24), 256, 0, stream>>>(xb, wqkvb, qbh, kbh, vt,
                                                    q_scale, k_scale, rope_cos, rope_sin);
    flash_mfma<<<dim3((S_/128)*B_*H_*SPLIT_), 256, 0, stream>>>(qbh, kbh, vt, po, pl);
    gemm_out<<<dim3((M_/64)*(D_/128)), 256, 0, stream>>>(po, pl, wob, out);
}

// Round 10
// 207.457 us; speedup vs baseline: 1.1057x; 1.1057x over previous
//
#include <hip/hip_runtime.h>
#include <hip/hip_bf16.h>

// RoPEAttention B=2 S=2048 D=1024 H=16 HD=64, fp32 in/out.
// R10: revert R9's GEMM XCD swizzles (per-XCD working set > 4MB L2 -> thrash)
//      and flash to R8 config. New: gemm_qkv BK=64 via XOR-swizzled gld16
//      (permute per-lane global pointers; slot row*8+(kch^(row&7))) -> half the
//      barriers, 32 MFMA/wave/barrier, conflict-free frag reads (2-way).
// ws (shorts): qbh[0,4M) kbh[4M,8M) vt[8M,12M) xb[16M,20M)
//              wqkvb[20M,23M) wob[23M,24M) po[24M,32M) pl(fp32) after.

#define B_ 2
#define S_ 2048
#define D_ 1024
#define H_ 16
#define HD_ 64
#define M_ (B_*S_)
#define SPLIT_ 2
#define KSPAN_ (S_/SPLIT_)    // 1024 keys per split

typedef __attribute__((ext_vector_type(8))) short short8;
typedef __attribute__((ext_vector_type(4))) short short4v;
typedef __attribute__((ext_vector_type(4))) float f32x4;
typedef __attribute__((ext_vector_type(4))) _Float16 half4;
typedef __attribute__((ext_vector_type(8))) _Float16 half8;

static __device__ __forceinline__ short f2bf(float f) {
    __hip_bfloat16 h = __float2bfloat16(f);
    return *reinterpret_cast<short*>(&h);
}
static __device__ __forceinline__ short f2h(float f) {
    _Float16 h = (_Float16)f;
    return *reinterpret_cast<short*>(&h);
}

typedef __attribute__((address_space(1))) const unsigned int gu32_t;
typedef __attribute__((address_space(3))) unsigned int lu32_t;
static __device__ __forceinline__ void gld16(const short* g, short* l) {
    __builtin_amdgcn_global_load_lds((gu32_t*)g, (lu32_t*)l, 16, 0, 0);
}

// ---------------- fp32 -> bf16 convert: x, wq|wk|wv (concat), wo ----------------
__global__ __launch_bounds__(256)
void convert_bf16(const float* __restrict__ x,
                  const float* __restrict__ wq, const float* __restrict__ wk,
                  const float* __restrict__ wv, const float* __restrict__ wo,
                  short* __restrict__ xb, short* __restrict__ wqkvb, short* __restrict__ wob)
{
    const size_t t4 = ((size_t)blockIdx.x * 256 + threadIdx.x) * 4;
    const float* src; short* dst; size_t off, doff;
    if (t4 < 4194304)      { src = x;  dst = xb;    off = t4;           doff = t4; }
    else if (t4 < 5242880) { src = wq; dst = wqkvb; off = t4 - 4194304; doff = t4 - 4194304; }
    else if (t4 < 6291456) { src = wk; dst = wqkvb; off = t4 - 5242880; doff = t4 - 4194304; }
    else if (t4 < 7340032) { src = wv; dst = wqkvb; off = t4 - 6291456; doff = t4 - 4194304; }
    else                   { src = wo; dst = wob;   off = t4 - 7340032; doff = t4 - 7340032; }
    float4 v = *(const float4*)(src + off);
    short4v s = { f2bf(v.x), f2bf(v.y), f2bf(v.z), f2bf(v.w) };
    *(short4v*)(dst + doff) = s;
}

// ---------------- bf16 MFMA GEMM NT 128x128, BK=64 XOR-swizzled (qkv fused, N=3072) ----------------
// Epilogue: which==0/1 -> fused RMSNorm+RoPE -> Qb/Kb bf16 [B,H,S,HD]
//           which==2   -> Vt f16 [B,H,HD,S]
__global__ __launch_bounds__(256)
void gemm_qkv(const short* __restrict__ A, const short* __restrict__ Bw,
              short* __restrict__ Qb, short* __restrict__ Kb, short* __restrict__ Vt,
              const float* __restrict__ q_scale, const float* __restrict__ k_scale,
              const float* __restrict__ rope_cos, const float* __restrict__ rope_sin)
{
    __shared__ __align__(16) short As[128*64];
    __shared__ __align__(16) short Bs[128*64];
    const int tid = threadIdx.x;
    const int w = tid >> 6, lane = tid & 63, quad = lane >> 4, l16 = lane & 15;
    const int wr = w >> 1, wc = w & 1;
    const int bm0 = blockIdx.x * 128, bn0 = blockIdx.y * 128;

    // gld16 staging, 4 calls each for A/B. Call j stages slots p=j*256+tid:
    // row = p>>3 (=j*32 + tid>>3), kslot = p&7; slot holds chunk kch = kslot ^ (row&7).
    const int row_ = tid >> 3;
    const int kslot = tid & 7;
    const short* gA[4]; const short* gB[4];
    #pragma unroll
    for (int j = 0; j < 4; ++j) {
        const int row = j*32 + row_;
        const int kch = kslot ^ (row & 7);
        gA[j] = A  + (size_t)(bm0 + row) * 1024 + kch*8;
        gB[j] = Bw + (size_t)(bn0 + row) * 1024 + kch*8;
    }

    f32x4 acc[4][4];
    #pragma unroll
    for (int i = 0; i < 4; ++i)
        #pragma unroll
        for (int j = 0; j < 4; ++j) acc[i][j] = (f32x4){0.f,0.f,0.f,0.f};

    for (int k0 = 0; k0 < 1024; k0 += 64) {
        __syncthreads();
        #pragma unroll
        for (int j = 0; j < 4; ++j) {
            gld16(gA[j] + k0, As + j*2048 + w*512);
            gld16(gB[j] + k0, Bs + j*2048 + w*512);
        }
        __syncthreads();
        short8 af[2][4], bfr[2][4];
        #pragma unroll
        for (int ph = 0; ph < 2; ++ph)
            #pragma unroll
            for (int i = 0; i < 4; ++i) {
                const int ra = wr*64 + i*16 + l16;
                af[ph][i]  = *(const short8*)(As + ra*64 + (((ph*4 + quad) ^ (ra & 7)) << 3));
                const int rb = wc*64 + i*16 + l16;
                bfr[ph][i] = *(const short8*)(Bs + rb*64 + (((ph*4 + quad) ^ (rb & 7)) << 3));
            }
        #pragma unroll
        for (int ph = 0; ph < 2; ++ph)
            #pragma unroll
            for (int i = 0; i < 4; ++i)
                #pragma unroll
                for (int j = 0; j < 4; ++j)
                    acc[i][j] = __builtin_amdgcn_mfma_f32_16x16x32_bf16(af[ph][i], bfr[ph][j], acc[i][j], 0, 0, 0);
    }

    // wave-uniform: this wave's 64 n-columns = one (which, head) pair
    const int nbase = bn0 + wc*64;
    const int which = nbase >> 10;
    const int h     = (nbase & 1023) >> 6;

    if (which < 2) {
        const float* sc = which ? k_scale : q_scale;
        short* dst      = which ? Kb : Qb;
        const float fold = which ? 1.0f : 0.18033688011112042f;  // q: (1/8)*log2(e)
        float scv[4];
        #pragma unroll
        for (int j = 0; j < 4; ++j) scv[j] = sc[j*16 + l16];
        #pragma unroll
        for (int i = 0; i < 4; ++i) {
            #pragma unroll
            for (int r = 0; r < 4; ++r) {
                const int m = bm0 + wr*64 + i*16 + quad*4 + r;
                const int b = m >> 11, s = m & (S_-1);
                float ss = 0.f;
                #pragma unroll
                for (int j = 0; j < 4; ++j) ss += acc[i][j][r] * acc[i][j][r];
                #pragma unroll
                for (int msk = 1; msk <= 8; msk <<= 1) ss += __shfl_xor(ss, msk, 64);
                const float rn = rsqrtf(ss * (1.0f/64.0f) + 1e-6f);
                #pragma unroll
                for (int j = 0; j < 4; ++j) {
                    const int hd = j*16 + l16;
                    const float nv = acc[i][j][r] * rn * scv[j];
                    const float c  = rope_cos[s*32 + (hd >> 1)];
                    const float sn = rope_sin[s*32 + (hd >> 1)];
                    const float partner = __shfl_xor(nv, 1, 64);
                    const float o = (hd & 1) ? (partner * sn + nv * c) : (nv * c - partner * sn);
                    dst[(((size_t)b*H_ + h)*S_ + s)*HD_ + hd] = f2bf(o * fold);
                }
            }
        }
    } else {
        #pragma unroll
        for (int i = 0; i < 4; ++i)
            #pragma unroll
            for (int r = 0; r < 4; ++r) {
                const int m = bm0 + wr*64 + i*16 + quad*4 + r;
                const int b = m >> 11, s = m & (S_-1);
                #pragma unroll
                for (int j = 0; j < 4; ++j) {
                    const int hd = j*16 + l16;
                    Vt[(((size_t)b*H_ + h)*HD_ + hd)*S_ + s] = f2h(acc[i][j][r]);
                }
            }
    }
}

// ---------------- out-proj GEMM 64x128, combine fused, po register-prefetch ----------------
__global__ __launch_bounds__(256)
void gemm_out(const short* __restrict__ po, const float* __restrict__ pl,
              const short* __restrict__ Bw, float* __restrict__ C)
{
    __shared__ __align__(16) short As[64*32];
    __shared__ __align__(16) short Bs[128*32];
    const int tid = threadIdx.x;
    const int w = tid >> 6, lane = tid & 63, quad = lane >> 4, l16 = lane & 15;
    const int bm0 = blockIdx.x * 64, bn0 = blockIdx.y * 128;

    const int srow = tid >> 2;
    const int skch = (tid & 3) * 8;
    const int m = bm0 + srow;
    const int b = m >> 11, s = m & (S_-1);
    const short* gB0 = Bw + (size_t)(bn0 + srow) * 1024 + skch;
    const short* gB1 = Bw + (size_t)(bn0 + 64 + srow) * 1024 + skch;
    short* lB0 = Bs + w*512;
    short* lB1 = Bs + 2048 + w*512;

    float inv[16];
    #pragma unroll
    for (int h = 0; h < 16; ++h)
        inv[h] = 1.0f / (pl[((size_t)(b*16 + h))*S_ + s] + pl[65536 + ((size_t)(b*16 + h))*S_ + s]);

    f32x4 acc[4][2];
    #pragma unroll
    for (int i = 0; i < 4; ++i) {
        acc[i][0] = (f32x4){0.f,0.f,0.f,0.f};
        acc[i][1] = (f32x4){0.f,0.f,0.f,0.f};
    }

    // prefetch k0=0 po chunks
    half8 c0 = *(const half8*)(po +            (size_t)m*1024 + skch);
    half8 c1 = *(const half8*)(po + 4194304 + (size_t)m*1024 + skch);

    for (int k0 = 0; k0 < 1024; k0 += 32) {
        const int h = k0 >> 6;          // head uniform per iter (skch+7 <= 31)
        short8 a;
        #pragma unroll
        for (int j = 0; j < 8; ++j)
            a[j] = f2bf(((float)c0[j] + (float)c1[j]) * inv[h]);
        __syncthreads();
        *(short8*)(As + srow*32 + skch) = a;
        gld16(gB0 + k0, lB0);
        gld16(gB1 + k0, lB1);
        __syncthreads();
        if (k0 < 1024 - 32) {           // issue next po loads before MFMA block
            c0 = *(const half8*)(po +            (size_t)m*1024 + k0 + 32 + skch);
            c1 = *(const half8*)(po + 4194304 + (size_t)m*1024 + k0 + 32 + skch);
        }
        short8 af[4], bfr[2];
        #pragma unroll
        for (int i = 0; i < 4; ++i)
            af[i] = *(const short8*)(As + (i*16 + l16)*32 + quad*8);
        #pragma unroll
        for (int j = 0; j < 2; ++j)
            bfr[j] = *(const short8*)(Bs + (w*32 + j*16 + l16)*32 + quad*8);
        #pragma unroll
        for (int i = 0; i < 4; ++i)
            #pragma unroll
            for (int j = 0; j < 2; ++j)
                acc[i][j] = __builtin_amdgcn_mfma_f32_16x16x32_bf16(af[i], bfr[j], acc[i][j], 0, 0, 0);
    }

    #pragma unroll
    for (int i = 0; i < 4; ++i)
        #pragma unroll
        for (int r = 0; r < 4; ++r) {
            const int mm = bm0 + i*16 + quad*4 + r;
            #pragma unroll
            for (int j = 0; j < 2; ++j) {
                const int n = bn0 + w*32 + j*16 + l16;
                C[(size_t)mm*1024 + n] = acc[i][j][r];
            }
        }
}

// ---------------- MFMA flash attention partial, split-K=2, XCD-swizzled (R8 config) ----------------
__global__ __launch_bounds__(256)
void flash_mfma(const short* __restrict__ qb, const short* __restrict__ kb,
                const short* __restrict__ vt, short* __restrict__ po, float* __restrict__ pl)
{
    __shared__ __align__(16) short Ks[64*64];
    __shared__ __align__(16) short Vs[64*64];   // f16 bits, [d][key] swizzled

    const int id   = blockIdx.x;
    const int xcd  = id & 7;
    const int rest = id >> 3;
    const int qblk = rest & 15;               // 16 q-blocks of 128
    const int g    = (rest >> 4) * 8 + xcd;   // (bh,sp) group 0..63
    const int bh   = g >> 1;
    const int sp   = g & 1;

    const int tid  = threadIdx.x;
    const int wv   = tid >> 6;
    const int lane = tid & 63;
    const int quad = lane >> 4;
    const int l16  = lane & 15;
    const int b    = bh >> 4, h = bh & (H_-1);
    const int q0   = qblk * 128 + wv * 32;
    const int kt0  = sp * KSPAN_;
    const size_t hbase = (size_t)bh * S_ * HD_;
    const size_t vbase = (size_t)bh * HD_ * S_;
    short* po_sp = po + (size_t)sp * 4194304;
    float* pl_sp = pl + (size_t)sp * 65536;

    const int c0r = tid >> 3,       c0c = tid & 7;
    const int c1r = (tid+256) >> 3, c1c = (tid+256) & 7;

    short8 qfrag[2][2];
    #pragma unroll
    for (int qf = 0; qf < 2; ++qf)
        #pragma unroll
        for (int c = 0; c < 2; ++c)
            qfrag[qf][c] = *(const short8*)(qb + hbase + (size_t)(q0 + qf*16 + l16)*HD_ + c*32 + quad*8);

    f32x4 Oacc[2][4];
    #pragma unroll
    for (int qf = 0; qf < 2; ++qf)
        #pragma unroll
        for (int dt = 0; dt < 4; ++dt) Oacc[qf][dt] = (f32x4){0.f,0.f,0.f,0.f};
    float l_lane[2] = {0.f, 0.f};

    short8 rk0 = *(const short8*)(kb + hbase + (size_t)(kt0 + c0r)*HD_ + c0c*8);
    short8 rk1 = *(const short8*)(kb + hbase + (size_t)(kt0 + c1r)*HD_ + c1c*8);
    short8 rv0 = *(const short8*)(vt + vbase + (size_t)c0r*S_ + kt0 + c0c*8);
    short8 rv1 = *(const short8*)(vt + vbase + (size_t)c1r*S_ + kt0 + c1c*8);

    #pragma unroll 1
    for (int t = 0; t < KSPAN_/64; ++t) {
        __syncthreads();
        *(short8*)(Ks + c0r*64 + ((c0c ^ (c0r & 7)) << 3)) = rk0;
        *(short8*)(Ks + c1r*64 + ((c1c ^ (c1r & 7)) << 3)) = rk1;
        *(short8*)(Vs + c0r*64 + ((c0c ^ (c0r & 7)) << 3)) = rv0;
        *(short8*)(Vs + c1r*64 + ((c1c ^ (c1r & 7)) << 3)) = rv1;
        __syncthreads();
        if (t < KSPAN_/64 - 1) {
            const int ktn = kt0 + (t+1)*64;
            rk0 = *(const short8*)(kb + hbase + (size_t)(ktn + c0r)*HD_ + c0c*8);
            rk1 = *(const short8*)(kb + hbase + (size_t)(ktn + c1r)*HD_ + c1c*8);
            rv0 = *(const short8*)(vt + vbase + (size_t)c0r*S_ + ktn + c0c*8);
            rv1 = *(const short8*)(vt + vbase + (size_t)c1r*S_ + ktn + c1c*8);
        }

        #pragma unroll
        for (int st = 0; st < 4; ++st) {
            short8 kf0 = *(const short8*)(Ks + (st*16 + l16)*64 + (((quad    ) ^ (l16 & 7)) << 3));
            short8 kf1 = *(const short8*)(Ks + (st*16 + l16)*64 + (((4 + quad) ^ (l16 & 7)) << 3));
            const int ch16 = st*2 + (quad >> 1);
            const int sw   = ((ch16 ^ (l16 & 7)) << 3) + (quad & 1)*4;
            half4 va[4];
            #pragma unroll
            for (int dt = 0; dt < 4; ++dt)
                va[dt] = *(const half4*)(Vs + (dt*16 + l16)*64 + sw);
            #pragma unroll
            for (int qf = 0; qf < 2; ++qf) {
                f32x4 acc = (f32x4){0.f,0.f,0.f,0.f};
                acc = __builtin_amdgcn_mfma_f32_16x16x32_bf16(kf0, qfrag[qf][0], acc, 0, 0, 0);
                acc = __builtin_amdgcn_mfma_f32_16x16x32_bf16(kf1, qfrag[qf][1], acc, 0, 0, 0);
                half4 pb;
                #pragma unroll
                for (int r = 0; r < 4; ++r) {
                    float p = __builtin_amdgcn_exp2f(acc[r] - 12.0f);
                    l_lane[qf] += p;
                    pb[r] = (_Float16)p;
                }
                #pragma unroll
                for (int dt = 0; dt < 4; ++dt)
                    Oacc[qf][dt] = __builtin_amdgcn_mfma_f32_16x16x16f16(va[dt], pb, Oacc[qf][dt], 0, 0, 0);
            }
        }
    }

    #pragma unroll
    for (int qf = 0; qf < 2; ++qf) {
        l_lane[qf] += __shfl_xor(l_lane[qf], 16, 64);
        l_lane[qf] += __shfl_xor(l_lane[qf], 32, 64);
        if (quad == 0) pl_sp[(size_t)bh*S_ + q0 + qf*16 + l16] = l_lane[qf];
    }
    #pragma unroll
    for (int qf = 0; qf < 2; ++qf) {
        const int s = q0 + qf*16 + l16;
        #pragma unroll
        for (int dt = 0; dt < 4; ++dt) {
            short4v o;
            #pragma unroll
            for (int r = 0; r < 4; ++r) o[r] = f2h(Oacc[qf][dt][r]);
            *(short4v*)(po_sp + (((size_t)b*S_ + s)*H_ + h)*HD_ + dt*16 + quad*4) = o;
        }
    }
}

extern "C" void kernel_launch(void* const* d_in, const int* in_sizes, int n_in,
                              void* d_out, int out_size, void* d_ws, size_t ws_size,
                              hipStream_t stream)
{
    (void)in_sizes; (void)n_in; (void)out_size; (void)ws_size;
    const float* x        = (const float*)d_in[0];
    const float* wq       = (const float*)d_in[1];
    const float* wk       = (const float*)d_in[2];
    const float* wv       = (const float*)d_in[3];
    const float* wo       = (const float*)d_in[4];
    const float* q_scale  = (const float*)d_in[5];
    const float* k_scale  = (const float*)d_in[6];
    const float* rope_cos = (const float*)d_in[7];
    const float* rope_sin = (const float*)d_in[8];
    float* out = (float*)d_out;
    short* ws  = (short*)d_ws;

    short* qbh   = ws;                 // 4M shorts
    short* kbh   = ws + 4194304;
    short* vt    = ws + 8388608;
    short* xb    = ws + 16777216;
    short* wqkvb = ws + 20971520;      // 3M shorts
    short* wob   = ws + 24117248;      // 1M shorts
    short* po    = ws + 25165824;      // 2 x 4M shorts (f16)
    float* pl    = (float*)(ws + 33554432);  // 2 x 64K floats

    convert_bf16<<<dim3(8192), 256, 0, stream>>>(x, wq, wk, wv, wo, xb, wqkvb, wob);
    gemm_qkv<<<dim3(M_/128, 24), 256, 0, stream>>>(xb, wqkvb, qbh, kbh, vt,
                                                   q_scale, k_scale, rope_cos, rope_sin);
    flash_mfma<<<dim3((S_/128)*B_*H_*SPLIT_), 256, 0, stream>>>(qbh, kbh, vt, po, pl);
    gemm_out<<<dim3(M_/64, D_/128), 256, 0, stream>>>(po, pl, wob, out);
}